// Round 4
// baseline (47.728 us; speedup 1.0000x reference)
//
#include <hip/hip_runtime.h>

#define HAD_D 4096

typedef float floatx4 __attribute__((ext_vector_type(4)));

// DPP quad_perm cross-lane XOR (pure VALU, no LDS pipe):
// 0xB1 = [1,0,3,2] = lane^1, 0x4E = [2,3,0,1] = lane^2.
__device__ __forceinline__ float dpp_xor1(float x) {
    return __builtin_bit_cast(float,
        __builtin_amdgcn_mov_dpp(__builtin_bit_cast(int, x), 0xB1, 0xF, 0xF, true));
}
__device__ __forceinline__ float dpp_xor2(float x) {
    return __builtin_bit_cast(float,
        __builtin_amdgcn_mov_dpp(__builtin_bit_cast(int, x), 0x4E, 0xF, 0xF, true));
}

// One wave per row. Phase-1 ownership (coalesced load): e = 256k + 4*lane + m.
//   reg-local stages: h=1,2 (m bits) and h=256..2048 (k bits).
// T1 LDS transpose swaps lane bits e[7:4] <-> reg bits e[11:8]:
//   phase-2 ownership: lane2 = 4*K + t  (K=e[11:8], t=e[7:6]), regs (u=e[5:2], m).
//   reg-local stages: h=4..32 (u bits); h=64,128 via DPP quad_perm (t = lane2[1:0]).
// T2 transposes back so stores are coalesced (+nontemporal).
// LDS layout (per wave, 4096 floats): float-addr A(k,l,m) = k*256 + pi_k(l)*4 + m,
//   pi_k(l) = (t2<<4) | (l&8) | ((l&7) ^ (t2<<1) ^ (k&1)),  t2 = l>>4.
// pi is bijective per k; all four DS phases (2 writes, 2 reads) are
// bank-conflict-free: every 8-consecutive-lane group covers 8 distinct 16B slots.
__global__ __launch_bounds__(128) void fwht4096_kernel(const float* __restrict__ x,
                                                       float* __restrict__ out,
                                                       int nrows) {
    __shared__ __align__(16) float lds[2 * HAD_D];
    const int wave = threadIdx.x >> 6;
    const int lane = threadIdx.x & 63;
    const int row  = blockIdx.x * 2 + wave;   // grid sized exactly: nrows even
    float* wlds = lds + wave * HAD_D;

    const floatx4* __restrict__ x4 = (const floatx4*)(x + (size_t)row * HAD_D);
    floatx4* __restrict__ y4       = (floatx4*)(out + (size_t)row * HAD_D);

    floatx4 v[16];
    #pragma unroll
    for (int k = 0; k < 16; ++k) v[k] = x4[k * 64 + lane];

    // Stages h=1,2 (within each float4).
    #pragma unroll
    for (int k = 0; k < 16; ++k) {
        float a = v[k].x, b = v[k].y, c = v[k].z, d = v[k].w;
        float a1 = a + b, b1 = a - b, c1 = c + d, d1 = c - d;
        v[k].x = a1 + c1; v[k].y = b1 + d1; v[k].z = a1 - c1; v[k].w = b1 - d1;
    }
    // Stages h=256..2048 (k index).
    #pragma unroll
    for (int s = 1; s <= 8; s <<= 1) {
        #pragma unroll
        for (int k = 0; k < 16; ++k) {
            if ((k & s) == 0) {
                floatx4 a = v[k], b = v[k ^ s];
                v[k] = a + b; v[k ^ s] = a - b;
            }
        }
    }

    // T1 write (16 x ds_write_b128, conflict-free).
    const int t2     = lane >> 4;
    const int pibase = (t2 << 4) | (lane & 8);
    const int xl     = (lane & 7) ^ (t2 << 1);
    #pragma unroll
    for (int k = 0; k < 16; ++k) {
        int pi = pibase | (xl ^ (k & 1));
        *(floatx4*)(wlds + k * 256 + pi * 4) = v[k];
    }
    __syncthreads();

    // T1 read (16 x ds_read_b128, conflict-free). Thread = (K, t).
    const int K      = lane >> 2;
    const int t      = lane & 3;
    const int rebase = K * 256;
    const int rxor   = (t << 1) | (K & 1);
    floatx4 w[16];
    #pragma unroll
    for (int u = 0; u < 16; ++u) {
        int pi = (t << 4) | (u & 8) | ((u & 7) ^ rxor);
        w[u] = *(const floatx4*)(wlds + rebase + pi * 4);
    }

    // Stages h=4..32 (u index).
    #pragma unroll
    for (int s = 1; s <= 8; s <<= 1) {
        #pragma unroll
        for (int u = 0; u < 16; ++u) {
            if ((u & s) == 0) {
                floatx4 a = w[u], b = w[u ^ s];
                w[u] = a + b; w[u ^ s] = a - b;
            }
        }
    }

    // Stage h=64: lane2-xor 1 (DPP quad_perm). low lane: own+partner; high: partner-own.
    {
        const float s1 = (lane & 1) ? -1.f : 1.f;
        #pragma unroll
        for (int u = 0; u < 16; ++u) {
            w[u].x = fmaf(s1, w[u].x, dpp_xor1(w[u].x));
            w[u].y = fmaf(s1, w[u].y, dpp_xor1(w[u].y));
            w[u].z = fmaf(s1, w[u].z, dpp_xor1(w[u].z));
            w[u].w = fmaf(s1, w[u].w, dpp_xor1(w[u].w));
        }
    }
    // Stage h=128: lane2-xor 2 (DPP quad_perm).
    {
        const float s2 = (lane & 2) ? -1.f : 1.f;
        #pragma unroll
        for (int u = 0; u < 16; ++u) {
            w[u].x = fmaf(s2, w[u].x, dpp_xor2(w[u].x));
            w[u].y = fmaf(s2, w[u].y, dpp_xor2(w[u].y));
            w[u].z = fmaf(s2, w[u].z, dpp_xor2(w[u].z));
            w[u].w = fmaf(s2, w[u].w, dpp_xor2(w[u].w));
        }
    }

    // T2 write (same addresses as T1 read).
    #pragma unroll
    for (int u = 0; u < 16; ++u) {
        int pi = (t << 4) | (u & 8) | ((u & 7) ^ rxor);
        *(floatx4*)(wlds + rebase + pi * 4) = w[u];
    }
    __syncthreads();

    // T2 read (same addresses as T1 write) + coalesced nontemporal store.
    #pragma unroll
    for (int k = 0; k < 16; ++k) {
        int pi = pibase | (xl ^ (k & 1));
        floatx4 o = *(const floatx4*)(wlds + k * 256 + pi * 4);
        __builtin_nontemporal_store(o, y4 + k * 64 + lane);
    }
}

extern "C" void kernel_launch(void* const* d_in, const int* in_sizes, int n_in,
                              void* d_out, int out_size, void* d_ws, size_t ws_size,
                              hipStream_t stream) {
    const float* x = (const float*)d_in[0];
    float* out     = (float*)d_out;
    const int nrows = in_sizes[0] / HAD_D;   // 8192 (even)
    const int blocks = nrows / 2;            // 2 rows (waves) per block
    hipLaunchKernelGGL(fwht4096_kernel, dim3(blocks), dim3(128), 0, stream,
                       x, out, nrows);
}